// Round 11
// baseline (1604.381 us; speedup 1.0000x reference)
//
#include <hip/hip_runtime.h>
#include <math.h>

#define SEQL 64
#define BATCHN 64
#define HID 1024
#define EMBD 1024
#define VOCAB 10000
#define G3 3072
#define NPAD 10240   // 80*128
#define AROWS 4096   // SEQL*BATCHN
#define HSLOT 65536  // BATCHN*HID elements per t-slot

typedef float f4v __attribute__((ext_vector_type(4)));
typedef unsigned short us4 __attribute__((ext_vector_type(4)));
typedef unsigned short us8 __attribute__((ext_vector_type(8)));
typedef __bf16 bf8v __attribute__((ext_vector_type(8)));

__device__ __forceinline__ unsigned short f2bf(float f) {
    unsigned u = __float_as_uint(f);
    u += 0x7fffu + ((u >> 16) & 1u);
    return (unsigned short)(u >> 16);
}
__device__ __forceinline__ float bf2f(unsigned short h) {
    return __uint_as_float(((unsigned)h) << 16);
}
__device__ __forceinline__ void split2(float f, unsigned short &hi, unsigned short &lo) {
    hi = f2bf(f);
    lo = f2bf(f - bf2f(hi));
}
__device__ __forceinline__ f4v mfma16(us8 a, us8 b, f4v c) {
    return __builtin_amdgcn_mfma_f32_16x16x32_bf16(
        __builtin_bit_cast(bf8v, a), __builtin_bit_cast(bf8v, b), c, 0, 0, 0);
}
__device__ __forceinline__ float sigmoidf_(float x) { return 1.f / (1.f + expf(-x)); }

// tiled layout for h within one t-slot: [(b>>4)*32 + (j>>5)][lane=((j>>3)&3)*16+(b&15)][e=j&7]
__device__ __forceinline__ size_t htile_off(int b, int j) {
    return ((size_t)((((b >> 4) * 32 + (j >> 5)) * 64) + ((j >> 3) & 3) * 16 + (b & 15))) * 8 + (j & 7);
}

// ---------------- prep: tile 4 weight matrices into MFMA B-fragment order ----------
// mats: 0=U0, 1=W1, 2=U1, 3=W0
__global__ __launch_bounds__(256)
void tile_weights_kernel(const float* __restrict__ U0, const float* __restrict__ W1,
                         const float* __restrict__ U1, const float* __restrict__ W0,
                         unsigned short* __restrict__ hi, unsigned short* __restrict__ lo)
{
    __shared__ float tile[32][65];
    const int mat = blockIdx.z;
    const float* src = (mat == 0) ? U0 : (mat == 1) ? W1 : (mat == 2) ? U1 : W0;
    const int n0 = blockIdx.x * 64, k0 = blockIdx.y * 32;
    const int t = threadIdx.x, tx = t & 63, ty = t >> 6;
#pragma unroll
    for (int s = 0; s < 8; s++)
        tile[ty * 8 + s][tx] = src[(size_t)(k0 + ty * 8 + s) * G3 + n0 + tx];
    __syncthreads();
    const int c = t >> 6, lane = t & 63, fr = lane & 15, kg = lane >> 4;
    const int cc = (n0 >> 4) + c;
    const size_t off = (((size_t)(mat * 192 + cc) * 32 + (k0 >> 5)) * 64 + lane) * 8;
    us8 h8, l8;
#pragma unroll
    for (int e = 0; e < 8; e++) {
        unsigned short a, b;
        split2(tile[kg * 8 + e][c * 16 + fr], a, b);
        h8[e] = a; l8[e] = b;
    }
    *(us8*)(hi + off) = h8;
    *(us8*)(lo + off) = l8;
}

// ---------------- prep (late): pad fcW to NPAD rows + hi/lo split ; fcb pad merged ----------
__global__ void fc_pad_split_kernel(const float* __restrict__ fcW,
                                    unsigned short* __restrict__ hi, unsigned short* __restrict__ lo,
                                    const float* __restrict__ fcb, float* __restrict__ fcb_pad)
{
    size_t g = (size_t)blockIdx.x * 256 + threadIdx.x;
    if (g < NPAD) fcb_pad[g] = (g < VOCAB) ? fcb[g] : 0.f;
    size_t i = g * 4;
    size_t row = i >> 10;
    f4v v = {0.f, 0.f, 0.f, 0.f};
    if (row < VOCAB) v = *(const f4v*)(fcW + i);
    us4 h, l;
#pragma unroll
    for (int j = 0; j < 4; j++) { unsigned short a, b; split2(v[j], a, b); h[j] = a; l[j] = b; }
    *(us4*)(hi + i) = h;
    *(us4*)(lo + i) = l;
}

// ---------------- prep: initial hidden -> tiled hi/lo ----------
__global__ void small_prep_kernel(const float* __restrict__ hidden,
                                  unsigned short* __restrict__ h0th, unsigned short* __restrict__ h0tl,
                                  unsigned short* __restrict__ h1th, unsigned short* __restrict__ h1tl)
{
    int idx = blockIdx.x * 256 + threadIdx.x;
    if (idx < BATCHN * HID) {
        int b = idx >> 10, j = idx & 1023;
        size_t o = htile_off(b, j);
        unsigned short a1, b1;
        split2(hidden[idx], a1, b1);                 h0th[o] = a1; h0tl[o] = b1;
        split2(hidden[BATCHN * HID + idx], a1, b1);  h1th[o] = a1; h1tl[o] = b1;
    }
}

// ---------------- GX0 = gather(emb,tok) @ W0 ----------
__global__ __launch_bounds__(256)
void gx0_gemm_kernel(const int* __restrict__ tok, const float* __restrict__ emb,
                     const unsigned short* __restrict__ Wthi, const unsigned short* __restrict__ Wtlo,
                     float* __restrict__ C)
{
    __shared__ unsigned short Ah[128][40], Al[128][40];
    const int bswz = blockIdx.x;
    const int xcd = bswz & 7, s = bswz >> 3;
    const int col0 = (xcd + 8 * (s >> 5)) * 128;   // 24 col-tiles
    const int row0 = (s & 31) * 128;               // 32 row-tiles
    const int tid = threadIdx.x;
    const int lane = tid & 63, wave = tid >> 6;
    const int wm = wave >> 1, wn = wave & 1;
    const int srow = tid >> 1;
    const int shalf = (tid & 1) * 16;

    const float* asrc = emb + (size_t)tok[row0 + srow] * EMBD + shalf;
    const int fr = lane & 15, fk = (lane >> 4) * 8;
    const int cc0 = (col0 >> 4) + wn * 4;

    f4v a[4];
#pragma unroll
    for (int q = 0; q < 4; q++) a[q] = *(const f4v*)(asrc + q * 4);

    f4v acc[4][4] = {};
    for (int k0 = 0; k0 < EMBD; k0 += 32) {
        __syncthreads();
        us8 ahv[2], alv[2];
#pragma unroll
        for (int q = 0; q < 4; q++)
#pragma unroll
            for (int j = 0; j < 4; j++) {
                unsigned short h, l;
                split2(a[q][j], h, l);
                ahv[q >> 1][(q & 1) * 4 + j] = h;
                alv[q >> 1][(q & 1) * 4 + j] = l;
            }
        *(us8*)(&Ah[srow][shalf]) = ahv[0];     *(us8*)(&Ah[srow][shalf + 8]) = ahv[1];
        *(us8*)(&Al[srow][shalf]) = alv[0];     *(us8*)(&Al[srow][shalf + 8]) = alv[1];
        __syncthreads();
        if (k0 + 32 < EMBD) {
#pragma unroll
            for (int q = 0; q < 4; q++) a[q] = *(const f4v*)(asrc + k0 + 32 + q * 4);
        }
        const int ks = k0 >> 5;
        us8 bfh[4], bfl[4];
#pragma unroll
        for (int n = 0; n < 4; n++) {
            const size_t bo = (((size_t)(3 * 192 + cc0 + n) * 32 + ks) * 64 + lane) * 8;
            bfh[n] = *(const us8*)(Wthi + bo);
            bfl[n] = *(const us8*)(Wtlo + bo);
        }
        us8 afh[4], afl[4];
#pragma unroll
        for (int m = 0; m < 4; m++) {
            afh[m] = *(const us8*)(&Ah[wm * 64 + m * 16 + fr][fk]);
            afl[m] = *(const us8*)(&Al[wm * 64 + m * 16 + fr][fk]);
        }
#pragma unroll
        for (int n = 0; n < 4; n++)
#pragma unroll
            for (int m = 0; m < 4; m++) {
                acc[m][n] = mfma16(afh[m], bfh[n], acc[m][n]);
                acc[m][n] = mfma16(afh[m], bfl[n], acc[m][n]);
                acc[m][n] = mfma16(afl[m], bfh[n], acc[m][n]);
            }
    }
    const int fq = lane >> 4;
#pragma unroll
    for (int m = 0; m < 4; m++)
#pragma unroll
        for (int n = 0; n < 4; n++)
#pragma unroll
            for (int i = 0; i < 4; i++) {
                int r = row0 + wm * 64 + m * 16 + fq * 4 + i;
                int c = col0 + wn * 64 + n * 16 + fr;
                C[(size_t)r * G3 + c] = acc[m][n][i];
            }
}

// ---------------- logits = H1 @ fcW^T + fcb ; 256x128 tile, 8 waves ----------
// Row-tiles (256 rows = 4 t-slots) pinned 2-per-XCD (A slice 2.1 MB -> L2-resident);
// each XCD walks its 80 col-tiles sequentially over the same B slice.
// B staged in LDS (proven R7 pattern); A direct from tiled per-t h1 fragments.
__global__ __launch_bounds__(512)
void logits_gemm_kernel(const unsigned short* __restrict__ h1t_hi, const unsigned short* __restrict__ h1t_lo,
                        const unsigned short* __restrict__ Bhi, const unsigned short* __restrict__ Blo,
                        const float* __restrict__ bias, float* __restrict__ C)
{
    __shared__ unsigned short Bh[128][40], Bl[128][40];
    const int bswz = blockIdx.x;               // 1280 = 8 xcd * 160
    const int xcd = bswz & 7, s = bswz >> 3;   // s 0..159
    const int rt = xcd + 8 * (s / 80);         // 16 row-tiles, 2 per XCD
    const int col0 = (s % 80) * 128;           // 80 col-tiles
    const int row0 = rt * 256;
    const int t0 = row0 >> 6;                  // 4 t-slots per tile
    const int tid = threadIdx.x;
    const int lane = tid & 63, wave = tid >> 6;
    const int wm = wave >> 1, wn = wave & 1;   // wm 0..3 (t-slot), wn 0..1 (col half)
    const int srow = tid >> 2;                 // 0..127 (stage row)
    const int skseg = (tid & 3) * 8;           // 0,8,16,24 (stage k-segment)

    const unsigned short* bh_src = Bhi + (size_t)(col0 + srow) * HID + skseg;
    const unsigned short* bl_src = Blo + (size_t)(col0 + srow) * HID + skseg;

    f4v acc[4][4] = {};
    us8 bh2 = *(const us8*)(bh_src);
    us8 bl2 = *(const us8*)(bl_src);

    const int fr = lane & 15, fk = (lane >> 4) * 8;
    const size_t abase = (size_t)(t0 + wm) * HSLOT + (size_t)lane * 8;

    for (int k0 = 0; k0 < HID; k0 += 32) {
        __syncthreads();
        *(us8*)(&Bh[srow][skseg]) = bh2;
        *(us8*)(&Bl[srow][skseg]) = bl2;
        __syncthreads();
        if (k0 + 32 < HID) {
            bh2 = *(const us8*)(bh_src + k0 + 32);
            bl2 = *(const us8*)(bl_src + k0 + 32);
        }
        const int ks = k0 >> 5;
        us8 afh[4], afl[4];
#pragma unroll
        for (int m = 0; m < 4; m++) {
            const size_t ao = abase + (size_t)(m * 32 + ks) * 512;
            afh[m] = *(const us8*)(h1t_hi + ao);
            afl[m] = *(const us8*)(h1t_lo + ao);
        }
#pragma unroll
        for (int n = 0; n < 4; n++) {
            us8 bfh = *(const us8*)(&Bh[wn * 64 + n * 16 + fr][fk]);
            us8 bfl = *(const us8*)(&Bl[wn * 64 + n * 16 + fr][fk]);
#pragma unroll
            for (int m = 0; m < 4; m++) {
                acc[m][n] = mfma16(afh[m], bfh, acc[m][n]);
                acc[m][n] = mfma16(afh[m], bfl, acc[m][n]);
                acc[m][n] = mfma16(afl[m], bfh, acc[m][n]);
            }
        }
    }
    const int fq = lane >> 4;
#pragma unroll
    for (int m = 0; m < 4; m++)
#pragma unroll
        for (int n = 0; n < 4; n++)
#pragma unroll
            for (int i = 0; i < 4; i++) {
                int r = row0 + wm * 64 + m * 16 + fq * 4 + i;
                int c = col0 + wn * 64 + n * 16 + fr;
                float v = acc[m][n][i] + bias[c];
                if (c < VOCAB) C[(size_t)r * VOCAB + c] = v;
            }
}

// ---------------- step GEMM: grid 512 = 64 jc x 8 kh, 256 thr (R10, proven) ----------
template <int T0, int T1>
__global__ __launch_bounds__(256)
void step_gemm_kernel(const unsigned short* __restrict__ h0hi, const unsigned short* __restrict__ h0lo,
                      const unsigned short* __restrict__ h1hi, const unsigned short* __restrict__ h1lo,
                      const unsigned short* __restrict__ Wthi, const unsigned short* __restrict__ Wtlo,
                      float* __restrict__ P)
{
    const int tid = threadIdx.x, lane = tid & 63, wave = tid >> 6;
    const int jc = blockIdx.x >> 3, kh = blockIdx.x & 7;
    const int ks = kh * 4 + wave;
    const size_t abase = ((size_t)ks * 64 + lane) * 8;

    f4v acc[9][4] = {};
    us8 ah[4], al[4];

    if (T0 < 6) {
#pragma unroll
        for (int m = 0; m < 4; m++) {
            ah[m] = *(const us8*)(h0hi + abase + (size_t)m * 16384);
            al[m] = *(const us8*)(h0lo + abase + (size_t)m * 16384);
        }
#pragma unroll
        for (int t2 = T0; t2 < ((T1 < 6) ? T1 : 6); ++t2) {
            const int mat = t2 / 3, g = t2 % 3;
            const size_t base = (((size_t)(mat * 192 + g * 64 + jc) * 32 + ks) * 64 + lane) * 8;
            us8 bh = *(const us8*)(Wthi + base);
            us8 bl = *(const us8*)(Wtlo + base);
#pragma unroll
            for (int m = 0; m < 4; ++m) {
                acc[t2][m] = mfma16(ah[m], bh, acc[t2][m]);
                acc[t2][m] = mfma16(ah[m], bl, acc[t2][m]);
                acc[t2][m] = mfma16(al[m], bh, acc[t2][m]);
            }
        }
    }
    if (T1 > 6) {
#pragma unroll
        for (int m = 0; m < 4; m++) {
            ah[m] = *(const us8*)(h1hi + abase + (size_t)m * 16384);
            al[m] = *(const us8*)(h1lo + abase + (size_t)m * 16384);
        }
#pragma unroll
        for (int t2 = 6; t2 < T1; ++t2) {
            const int g = t2 % 3;
            const size_t base = (((size_t)(2 * 192 + g * 64 + jc) * 32 + ks) * 64 + lane) * 8;
            us8 bh = *(const us8*)(Wthi + base);
            us8 bl = *(const us8*)(Wtlo + base);
#pragma unroll
            for (int m = 0; m < 4; ++m) {
                acc[t2][m] = mfma16(ah[m], bh, acc[t2][m]);
                acc[t2][m] = mfma16(ah[m], bl, acc[t2][m]);
                acc[t2][m] = mfma16(al[m], bh, acc[t2][m]);
            }
        }
    }

    __shared__ f4v red[4][2][4][64];
    const int rrow = (lane >> 4) * 4, rcol = lane & 15;
#pragma unroll
    for (int c = 0; c < 5; ++c) {
        const int ta = 2 * c, tb = 2 * c + 1;
        if (tb >= T0 && ta < T1) {
#pragma unroll
            for (int u = 0; u < 2; ++u) {
                const int t2 = 2 * c + u;
                if (t2 >= T0 && t2 < T1) {
#pragma unroll
                    for (int m = 0; m < 4; ++m)
                        red[wave][u][m][lane] = acc[t2][m];
                }
            }
            __syncthreads();
#pragma unroll
            for (int s2 = 0; s2 < 2; ++s2) {
                const int combo = wave * 2 + s2;       // 0..7
                const int u = combo >> 2, m = combo & 3;
                const int t2 = 2 * c + u;
                if (t2 >= T0 && t2 < T1) {
                    f4v v = (red[0][u][m][lane] + red[1][u][m][lane])
                          + (red[2][u][m][lane] + red[3][u][m][lane]);
#pragma unroll
                    for (int i = 0; i < 4; ++i)
                        P[(((size_t)kh * 9 + t2) * 64 + (m * 16 + rrow + i)) * 1024 + jc * 16 + rcol]
                            = v[i];
                }
            }
            __syncthreads();
        }
    }
}

// ---------------- step reduce: sum 8 kh-partials + fused GRU pointwise ----------
// T0==3 instantiation (final step) also writes the hidden-state output block.
template <int T0, int T1>
__global__ __launch_bounds__(256)
void step_reduce_kernel(const float* __restrict__ P, const float* __restrict__ gx0next,
                        const float* __restrict__ bw0, const float* __restrict__ bu0,
                        const float* __restrict__ bw1, const float* __restrict__ bu1,
                        const unsigned short* __restrict__ h0hi, const unsigned short* __restrict__ h0lo,
                        const unsigned short* __restrict__ h1hi, const unsigned short* __restrict__ h1lo,
                        unsigned short* __restrict__ h0o_hi, unsigned short* __restrict__ h0o_lo,
                        unsigned short* __restrict__ h1o_hi, unsigned short* __restrict__ h1o_lo,
                        float* __restrict__ outF)
{
    const int idx = blockIdx.x * 256 + threadIdx.x;
    const int b = idx >> 10, j = idx & 1023;
    float G[9];
#pragma unroll
    for (int t2 = T0; t2 < T1; t2++) {
        const float* p = P + ((size_t)t2 * 64 + b) * 1024 + j;
        float s0 = 0.f, s1 = 0.f;
#pragma unroll
        for (int kh = 0; kh < 4; kh++) {
            s0 += p[(size_t)(kh * 9) * 64 * 1024];
            s1 += p[(size_t)((kh + 4) * 9) * 64 * 1024];
        }
        G[t2] = s0 + s1;
    }
    const size_t po = htile_off(b, j);
    if (T0 == 0) {
        float sr  = gx0next[(size_t)b * G3 + j]            + bw0[j]           + G[0] + bu0[j];
        float sz  = gx0next[(size_t)b * G3 + HID + j]      + bw0[HID + j]     + G[1] + bu0[HID + j];
        float gxn = gx0next[(size_t)b * G3 + 2 * HID + j]  + bw0[2 * HID + j];
        float ghn = G[2] + bu0[2 * HID + j];
        float r = sigmoidf_(sr);
        float z = sigmoidf_(sz);
        float ht = tanhf(gxn + r * ghn);
        float hp = bf2f(h0hi[po]) + bf2f(h0lo[po]);
        float hn = (1.f - z) * hp + z * ht;
        unsigned short hh, hl2; split2(hn, hh, hl2);
        h0o_hi[po] = hh; h0o_lo[po] = hl2;
    }
    if (T1 > 3) {
        float sr  = G[3] + bw1[j]           + G[6] + bu1[j];
        float sz  = G[4] + bw1[HID + j]     + G[7] + bu1[HID + j];
        float gxn = G[5] + bw1[2 * HID + j];
        float ghn = G[8] + bu1[2 * HID + j];
        float r = sigmoidf_(sr);
        float z = sigmoidf_(sz);
        float ht = tanhf(gxn + r * ghn);
        float hp = bf2f(h1hi[po]) + bf2f(h1lo[po]);
        float hn = (1.f - z) * hp + z * ht;
        unsigned short hh, hl2; split2(hn, hh, hl2);
        h1o_hi[po] = hh; h1o_lo[po] = hl2;
        if (T0 == 3) {   // final step: emit hidden output (h0_63 from inputs, h1_63 = hn)
            outF[(size_t)b * HID + j] = bf2f(h0hi[po]) + bf2f(h0lo[po]);
            outF[(size_t)BATCHN * HID + b * HID + j] = hn;
        }
    }
}

extern "C" void kernel_launch(void* const* d_in, const int* in_sizes, int n_in,
                              void* d_out, int out_size, void* d_ws, size_t ws_size,
                              hipStream_t stream)
{
    (void)in_sizes; (void)n_in; (void)out_size;
    const int*   tok    = (const int*)  d_in[0];
    const float* hidden = (const float*)d_in[1];
    const float* emb    = (const float*)d_in[2];
    const float* W0     = (const float*)d_in[3];
    const float* U0     = (const float*)d_in[4];
    const float* bw0    = (const float*)d_in[5];
    const float* bu0    = (const float*)d_in[6];
    const float* W1     = (const float*)d_in[7];
    const float* U1     = (const float*)d_in[8];
    const float* bw1    = (const float*)d_in[9];
    const float* bu1    = (const float*)d_in[10];
    const float* fcW    = (const float*)d_in[11];
    const float* fcb    = (const float*)d_in[12];
    float* out = (float*)d_out;

    char* wsp = (char*)d_ws;
    size_t used = 0;
    auto alloc = [&](size_t bytes) -> char* {
        char* p = wsp + used;
        used += (bytes + 255) & ~(size_t)255;
        return p;
    };
    unsigned short* Wt_hi = (unsigned short*)alloc((size_t)4 * G3 * HID * 2);   // 25.2 MB
    unsigned short* Wt_lo = (unsigned short*)alloc((size_t)4 * G3 * HID * 2);   // 25.2 MB
    float*          GX0   = (float*)alloc((size_t)AROWS * G3 * 4);              // 50.3 MB
    unsigned short* H0Thi = (unsigned short*)alloc((size_t)SEQL * HSLOT * 2);   // 8.4 MB
    unsigned short* H0Tlo = (unsigned short*)alloc((size_t)SEQL * HSLOT * 2);
    unsigned short* H1Thi = (unsigned short*)alloc((size_t)SEQL * HSLOT * 2);
    unsigned short* H1Tlo = (unsigned short*)alloc((size_t)SEQL * HSLOT * 2);
    float*          P     = (float*)alloc((size_t)8 * 9 * BATCHN * HID * 4);    // 18.9 MB
    unsigned short* h0ith = (unsigned short*)alloc((size_t)HSLOT * 2);
    unsigned short* h0itl = (unsigned short*)alloc((size_t)HSLOT * 2);
    unsigned short* h1ith = (unsigned short*)alloc((size_t)HSLOT * 2);
    unsigned short* h1itl = (unsigned short*)alloc((size_t)HSLOT * 2);
    if (used > ws_size) return;  // ~154 MB needed

    unsigned short* fcWhi = Wt_hi;   // fc split aliases dead Wt space (20.97 MB < 25.17 MB)
    unsigned short* fcWlo = Wt_lo;
    float*          fcbp  = (float*)((char*)Wt_hi + (size_t)NPAD * HID * 2);

    float* outHid = out + (size_t)AROWS * VOCAB;

    tile_weights_kernel<<<dim3(48, 32, 4), 256, 0, stream>>>(U0, W1, U1, W0, Wt_hi, Wt_lo);
    small_prep_kernel<<<256, 256, 0, stream>>>(hidden, h0ith, h0itl, h1ith, h1itl);
    gx0_gemm_kernel<<<768, 256, 0, stream>>>(tok, emb, Wt_hi, Wt_lo, GX0);

    // prologue: h0_0 = GRU0(gx0[0], h_init0)
    step_gemm_kernel<0, 3><<<512, 256, 0, stream>>>(
        h0ith, h0itl, h1ith, h1itl, Wt_hi, Wt_lo, P);
    step_reduce_kernel<0, 3><<<256, 256, 0, stream>>>(
        P, GX0, bw0, bu0, bw1, bu1,
        h0ith, h0itl, h1ith, h1itl,
        H0Thi, H0Tlo,                                       // h0_0 -> slot 0
        H1Thi + (size_t)63 * HSLOT, H1Tlo + (size_t)63 * HSLOT,   // unused (compiled out)
        outHid);

    for (int t = 0; t < 63; t++) {
        const unsigned short* h0h = H0Thi + (size_t)t * HSLOT;
        const unsigned short* h0l = H0Tlo + (size_t)t * HSLOT;
        const unsigned short* a1h = (t == 0) ? h1ith : H1Thi + (size_t)(t - 1) * HSLOT;
        const unsigned short* a1l = (t == 0) ? h1itl : H1Tlo + (size_t)(t - 1) * HSLOT;
        step_gemm_kernel<0, 9><<<512, 256, 0, stream>>>(
            h0h, h0l, a1h, a1l, Wt_hi, Wt_lo, P);
        step_reduce_kernel<0, 9><<<256, 256, 0, stream>>>(
            P, GX0 + (size_t)(t + 1) * BATCHN * G3, bw0, bu0, bw1, bu1,
            h0h, h0l, a1h, a1l,
            H0Thi + (size_t)(t + 1) * HSLOT, H0Tlo + (size_t)(t + 1) * HSLOT,  // h0_{t+1}
            H1Thi + (size_t)t * HSLOT, H1Tlo + (size_t)t * HSLOT,              // h1_t
            outHid);
    }
    // t = 63: layer-1 only; also emits hidden output (h0_63 + h1_63)
    step_gemm_kernel<3, 9><<<512, 256, 0, stream>>>(
        H0Thi + (size_t)63 * HSLOT, H0Tlo + (size_t)63 * HSLOT,
        H1Thi + (size_t)62 * HSLOT, H1Tlo + (size_t)62 * HSLOT,
        Wt_hi, Wt_lo, P);
    step_reduce_kernel<3, 9><<<256, 256, 0, stream>>>(
        P, GX0, bw0, bu0, bw1, bu1,
        H0Thi + (size_t)63 * HSLOT, H0Tlo + (size_t)63 * HSLOT,
        H1Thi + (size_t)62 * HSLOT, H1Tlo + (size_t)62 * HSLOT,
        h0ith, h0itl,                                              // unused (compiled out)
        H1Thi + (size_t)63 * HSLOT, H1Tlo + (size_t)63 * HSLOT,    // h1_63
        outHid);

    // fc prep (aliases dead Wt space), then logits
    fc_pad_split_kernel<<<NPAD, 256, 0, stream>>>(fcW, fcWhi, fcWlo, fcb, fcbp);
    logits_gemm_kernel<<<1280, 512, 0, stream>>>(
        H1Thi, H1Tlo, fcWhi, fcWlo, fcbp, out);
}

// Round 12
// 1562.987 us; speedup vs baseline: 1.0265x; 1.0265x over previous
//
#include <hip/hip_runtime.h>
#include <math.h>

#define SEQL 64
#define BATCHN 64
#define HID 1024
#define EMBD 1024
#define VOCAB 10000
#define G3 3072
#define NPAD 10240   // 80*128
#define AROWS 4096   // SEQL*BATCHN
#define HSLOT 65536  // BATCHN*HID elements per t-slot

typedef float f4v __attribute__((ext_vector_type(4)));
typedef unsigned short us4 __attribute__((ext_vector_type(4)));
typedef unsigned short us8 __attribute__((ext_vector_type(8)));
typedef __bf16 bf8v __attribute__((ext_vector_type(8)));

__device__ __forceinline__ unsigned short f2bf(float f) {
    unsigned u = __float_as_uint(f);
    u += 0x7fffu + ((u >> 16) & 1u);
    return (unsigned short)(u >> 16);
}
__device__ __forceinline__ float bf2f(unsigned short h) {
    return __uint_as_float(((unsigned)h) << 16);
}
__device__ __forceinline__ void split2(float f, unsigned short &hi, unsigned short &lo) {
    hi = f2bf(f);
    lo = f2bf(f - bf2f(hi));
}
__device__ __forceinline__ f4v mfma16(us8 a, us8 b, f4v c) {
    return __builtin_amdgcn_mfma_f32_16x16x32_bf16(
        __builtin_bit_cast(bf8v, a), __builtin_bit_cast(bf8v, b), c, 0, 0, 0);
}
__device__ __forceinline__ float sigmoidf_(float x) { return 1.f / (1.f + expf(-x)); }

// tiled layout for h within one t-slot: [(b>>4)*32 + (j>>5)][lane=((j>>3)&3)*16+(b&15)][e=j&7]
__device__ __forceinline__ size_t htile_off(int b, int j) {
    return ((size_t)((((b >> 4) * 32 + (j >> 5)) * 64) + ((j >> 3) & 3) * 16 + (b & 15))) * 8 + (j & 7);
}

// ---------------- prep: tile 4 weight matrices into MFMA B-fragment order ----------
// mats: 0=U0, 1=W1, 2=U1, 3=W0
__global__ __launch_bounds__(256)
void tile_weights_kernel(const float* __restrict__ U0, const float* __restrict__ W1,
                         const float* __restrict__ U1, const float* __restrict__ W0,
                         unsigned short* __restrict__ hi, unsigned short* __restrict__ lo)
{
    __shared__ float tile[32][65];
    const int mat = blockIdx.z;
    const float* src = (mat == 0) ? U0 : (mat == 1) ? W1 : (mat == 2) ? U1 : W0;
    const int n0 = blockIdx.x * 64, k0 = blockIdx.y * 32;
    const int t = threadIdx.x, tx = t & 63, ty = t >> 6;
#pragma unroll
    for (int s = 0; s < 8; s++)
        tile[ty * 8 + s][tx] = src[(size_t)(k0 + ty * 8 + s) * G3 + n0 + tx];
    __syncthreads();
    const int c = t >> 6, lane = t & 63, fr = lane & 15, kg = lane >> 4;
    const int cc = (n0 >> 4) + c;
    const size_t off = (((size_t)(mat * 192 + cc) * 32 + (k0 >> 5)) * 64 + lane) * 8;
    us8 h8, l8;
#pragma unroll
    for (int e = 0; e < 8; e++) {
        unsigned short a, b;
        split2(tile[kg * 8 + e][c * 16 + fr], a, b);
        h8[e] = a; l8[e] = b;
    }
    *(us8*)(hi + off) = h8;
    *(us8*)(lo + off) = l8;
}

// ---------------- prep (late): pad fcW to NPAD rows + hi/lo split ; fcb pad merged ----------
__global__ void fc_pad_split_kernel(const float* __restrict__ fcW,
                                    unsigned short* __restrict__ hi, unsigned short* __restrict__ lo,
                                    const float* __restrict__ fcb, float* __restrict__ fcb_pad)
{
    size_t g = (size_t)blockIdx.x * 256 + threadIdx.x;
    if (g < NPAD) fcb_pad[g] = (g < VOCAB) ? fcb[g] : 0.f;
    size_t i = g * 4;
    size_t row = i >> 10;
    f4v v = {0.f, 0.f, 0.f, 0.f};
    if (row < VOCAB) v = *(const f4v*)(fcW + i);
    us4 h, l;
#pragma unroll
    for (int j = 0; j < 4; j++) { unsigned short a, b; split2(v[j], a, b); h[j] = a; l[j] = b; }
    *(us4*)(hi + i) = h;
    *(us4*)(lo + i) = l;
}

// ---------------- prep: initial hidden -> tiled hi/lo ----------
__global__ void small_prep_kernel(const float* __restrict__ hidden,
                                  unsigned short* __restrict__ h0th, unsigned short* __restrict__ h0tl,
                                  unsigned short* __restrict__ h1th, unsigned short* __restrict__ h1tl)
{
    int idx = blockIdx.x * 256 + threadIdx.x;
    if (idx < BATCHN * HID) {
        int b = idx >> 10, j = idx & 1023;
        size_t o = htile_off(b, j);
        unsigned short a1, b1;
        split2(hidden[idx], a1, b1);                 h0th[o] = a1; h0tl[o] = b1;
        split2(hidden[BATCHN * HID + idx], a1, b1);  h1th[o] = a1; h1tl[o] = b1;
    }
}

// ---------------- GX0 = gather(emb,tok) @ W0 ----------
__global__ __launch_bounds__(256)
void gx0_gemm_kernel(const int* __restrict__ tok, const float* __restrict__ emb,
                     const unsigned short* __restrict__ Wthi, const unsigned short* __restrict__ Wtlo,
                     float* __restrict__ C)
{
    __shared__ unsigned short Ah[128][40], Al[128][40];
    const int bswz = blockIdx.x;
    const int xcd = bswz & 7, s = bswz >> 3;
    const int col0 = (xcd + 8 * (s >> 5)) * 128;   // 24 col-tiles
    const int row0 = (s & 31) * 128;               // 32 row-tiles
    const int tid = threadIdx.x;
    const int lane = tid & 63, wave = tid >> 6;
    const int wm = wave >> 1, wn = wave & 1;
    const int srow = tid >> 1;
    const int shalf = (tid & 1) * 16;

    const float* asrc = emb + (size_t)tok[row0 + srow] * EMBD + shalf;
    const int fr = lane & 15, fk = (lane >> 4) * 8;
    const int cc0 = (col0 >> 4) + wn * 4;

    f4v a[4];
#pragma unroll
    for (int q = 0; q < 4; q++) a[q] = *(const f4v*)(asrc + q * 4);

    f4v acc[4][4] = {};
    for (int k0 = 0; k0 < EMBD; k0 += 32) {
        __syncthreads();
        us8 ahv[2], alv[2];
#pragma unroll
        for (int q = 0; q < 4; q++)
#pragma unroll
            for (int j = 0; j < 4; j++) {
                unsigned short h, l;
                split2(a[q][j], h, l);
                ahv[q >> 1][(q & 1) * 4 + j] = h;
                alv[q >> 1][(q & 1) * 4 + j] = l;
            }
        *(us8*)(&Ah[srow][shalf]) = ahv[0];     *(us8*)(&Ah[srow][shalf + 8]) = ahv[1];
        *(us8*)(&Al[srow][shalf]) = alv[0];     *(us8*)(&Al[srow][shalf + 8]) = alv[1];
        __syncthreads();
        if (k0 + 32 < EMBD) {
#pragma unroll
            for (int q = 0; q < 4; q++) a[q] = *(const f4v*)(asrc + k0 + 32 + q * 4);
        }
        const int ks = k0 >> 5;
        us8 bfh[4], bfl[4];
#pragma unroll
        for (int n = 0; n < 4; n++) {
            const size_t bo = (((size_t)(3 * 192 + cc0 + n) * 32 + ks) * 64 + lane) * 8;
            bfh[n] = *(const us8*)(Wthi + bo);
            bfl[n] = *(const us8*)(Wtlo + bo);
        }
        us8 afh[4], afl[4];
#pragma unroll
        for (int m = 0; m < 4; m++) {
            afh[m] = *(const us8*)(&Ah[wm * 64 + m * 16 + fr][fk]);
            afl[m] = *(const us8*)(&Al[wm * 64 + m * 16 + fr][fk]);
        }
#pragma unroll
        for (int n = 0; n < 4; n++)
#pragma unroll
            for (int m = 0; m < 4; m++) {
                acc[m][n] = mfma16(afh[m], bfh[n], acc[m][n]);
                acc[m][n] = mfma16(afh[m], bfl[n], acc[m][n]);
                acc[m][n] = mfma16(afl[m], bfh[n], acc[m][n]);
            }
    }
    const int fq = lane >> 4;
#pragma unroll
    for (int m = 0; m < 4; m++)
#pragma unroll
        for (int n = 0; n < 4; n++)
#pragma unroll
            for (int i = 0; i < 4; i++) {
                int r = row0 + wm * 64 + m * 16 + fq * 4 + i;
                int c = col0 + wn * 64 + n * 16 + fr;
                C[(size_t)r * G3 + c] = acc[m][n][i];
            }
}

// ---------------- logits = H1 @ fcW^T + fcb ; R7 128x128 structure, fragment-order B stage ----------
// B staged in LDS in MFMA-fragment order: slot (n*64 + kg*16 + fr) = us8.
// Writes (Bf[tid]) and reads (Bf[(wn*4+n)*64 + lane]) are lane-contiguous 16B -> no pathological
// bank pattern (R7's [128][40] row-strided reads were 8-way: bank = 4*((row*5+kg)%8)).
__global__ __launch_bounds__(256)
void logits_gemm_kernel(const unsigned short* __restrict__ h1t_hi, const unsigned short* __restrict__ h1t_lo,
                        const unsigned short* __restrict__ Bhi, const unsigned short* __restrict__ Blo,
                        const float* __restrict__ bias, float* __restrict__ C)
{
    __shared__ us8 Bfh[512], Bfl[512];                 // 16 KB total
    const int bswz = blockIdx.x;
    const int xcd = bswz & 7, s = bswz >> 3;
    const int col0 = (xcd + 8 * (s >> 5)) * 128;   // 80 col-tiles
    const int row0 = (s & 31) * 128;               // 32 row-tiles
    const int t0 = row0 >> 6;                       // 2 t-slots per 128-row tile
    const int tid = threadIdx.x;
    const int lane = tid & 63, wave = tid >> 6;
    const int wm = wave >> 1, wn = wave & 1;

    // stage mapping: thread tid owns slots tid (rows col0+sn*16+sfr) and tid+256 (rows +64)
    const int sfr = tid & 15, skg = (tid >> 4) & 3, sn = tid >> 6;
    const size_t srow0 = (size_t)(col0 + sn * 16 + sfr) * HID + skg * 8;
    const size_t srow1 = srow0 + (size_t)64 * HID;

    us8 bh2[2], bl2[2];
    bh2[0] = *(const us8*)(Bhi + srow0);
    bh2[1] = *(const us8*)(Bhi + srow1);
    bl2[0] = *(const us8*)(Blo + srow0);
    bl2[1] = *(const us8*)(Blo + srow1);

    f4v acc[4][4] = {};
    const int fr = lane & 15;
    const size_t abase = (size_t)(t0 + wm) * HSLOT + (size_t)lane * 8;

    for (int k0 = 0; k0 < HID; k0 += 32) {
        __syncthreads();
        Bfh[tid] = bh2[0];  Bfh[tid + 256] = bh2[1];
        Bfl[tid] = bl2[0];  Bfl[tid + 256] = bl2[1];
        __syncthreads();
        if (k0 + 32 < HID) {
            bh2[0] = *(const us8*)(Bhi + srow0 + k0 + 32);
            bh2[1] = *(const us8*)(Bhi + srow1 + k0 + 32);
            bl2[0] = *(const us8*)(Blo + srow0 + k0 + 32);
            bl2[1] = *(const us8*)(Blo + srow1 + k0 + 32);
        }
        const int ks = k0 >> 5;
        us8 afh[4], afl[4];
#pragma unroll
        for (int m = 0; m < 4; m++) {
            const size_t ao = abase + (size_t)(m * 32 + ks) * 512;
            afh[m] = *(const us8*)(h1t_hi + ao);
            afl[m] = *(const us8*)(h1t_lo + ao);
        }
#pragma unroll
        for (int n = 0; n < 4; n++) {
            us8 bfh = Bfh[(wn * 4 + n) * 64 + lane];
            us8 bfl = Bfl[(wn * 4 + n) * 64 + lane];
#pragma unroll
            for (int m = 0; m < 4; m++) {
                acc[m][n] = mfma16(afh[m], bfh, acc[m][n]);
                acc[m][n] = mfma16(afh[m], bfl, acc[m][n]);
                acc[m][n] = mfma16(afl[m], bfh, acc[m][n]);
            }
        }
    }
    const int fq = lane >> 4;
#pragma unroll
    for (int m = 0; m < 4; m++)
#pragma unroll
        for (int n = 0; n < 4; n++)
#pragma unroll
            for (int i = 0; i < 4; i++) {
                int r = row0 + wm * 64 + m * 16 + fq * 4 + i;
                int c = col0 + wn * 64 + n * 16 + fr;
                float v = acc[m][n][i] + bias[c];
                if (c < VOCAB) C[(size_t)r * VOCAB + c] = v;
            }
}

// ---------------- step GEMM: grid 512 = 64 jc x 8 kh, 256 thr (R10, proven) ----------
template <int T0, int T1>
__global__ __launch_bounds__(256)
void step_gemm_kernel(const unsigned short* __restrict__ h0hi, const unsigned short* __restrict__ h0lo,
                      const unsigned short* __restrict__ h1hi, const unsigned short* __restrict__ h1lo,
                      const unsigned short* __restrict__ Wthi, const unsigned short* __restrict__ Wtlo,
                      float* __restrict__ P)
{
    const int tid = threadIdx.x, lane = tid & 63, wave = tid >> 6;
    const int jc = blockIdx.x >> 3, kh = blockIdx.x & 7;
    const int ks = kh * 4 + wave;
    const size_t abase = ((size_t)ks * 64 + lane) * 8;

    f4v acc[9][4] = {};
    us8 ah[4], al[4];

    if (T0 < 6) {
#pragma unroll
        for (int m = 0; m < 4; m++) {
            ah[m] = *(const us8*)(h0hi + abase + (size_t)m * 16384);
            al[m] = *(const us8*)(h0lo + abase + (size_t)m * 16384);
        }
#pragma unroll
        for (int t2 = T0; t2 < ((T1 < 6) ? T1 : 6); ++t2) {
            const int mat = t2 / 3, g = t2 % 3;
            const size_t base = (((size_t)(mat * 192 + g * 64 + jc) * 32 + ks) * 64 + lane) * 8;
            us8 bh = *(const us8*)(Wthi + base);
            us8 bl = *(const us8*)(Wtlo + base);
#pragma unroll
            for (int m = 0; m < 4; ++m) {
                acc[t2][m] = mfma16(ah[m], bh, acc[t2][m]);
                acc[t2][m] = mfma16(ah[m], bl, acc[t2][m]);
                acc[t2][m] = mfma16(al[m], bh, acc[t2][m]);
            }
        }
    }
    if (T1 > 6) {
#pragma unroll
        for (int m = 0; m < 4; m++) {
            ah[m] = *(const us8*)(h1hi + abase + (size_t)m * 16384);
            al[m] = *(const us8*)(h1lo + abase + (size_t)m * 16384);
        }
#pragma unroll
        for (int t2 = 6; t2 < T1; ++t2) {
            const int g = t2 % 3;
            const size_t base = (((size_t)(2 * 192 + g * 64 + jc) * 32 + ks) * 64 + lane) * 8;
            us8 bh = *(const us8*)(Wthi + base);
            us8 bl = *(const us8*)(Wtlo + base);
#pragma unroll
            for (int m = 0; m < 4; ++m) {
                acc[t2][m] = mfma16(ah[m], bh, acc[t2][m]);
                acc[t2][m] = mfma16(ah[m], bl, acc[t2][m]);
                acc[t2][m] = mfma16(al[m], bh, acc[t2][m]);
            }
        }
    }

    __shared__ f4v red[4][2][4][64];
    const int rrow = (lane >> 4) * 4, rcol = lane & 15;
#pragma unroll
    for (int c = 0; c < 5; ++c) {
        const int ta = 2 * c, tb = 2 * c + 1;
        if (tb >= T0 && ta < T1) {
#pragma unroll
            for (int u = 0; u < 2; ++u) {
                const int t2 = 2 * c + u;
                if (t2 >= T0 && t2 < T1) {
#pragma unroll
                    for (int m = 0; m < 4; ++m)
                        red[wave][u][m][lane] = acc[t2][m];
                }
            }
            __syncthreads();
#pragma unroll
            for (int s2 = 0; s2 < 2; ++s2) {
                const int combo = wave * 2 + s2;       // 0..7
                const int u = combo >> 2, m = combo & 3;
                const int t2 = 2 * c + u;
                if (t2 >= T0 && t2 < T1) {
                    f4v v = (red[0][u][m][lane] + red[1][u][m][lane])
                          + (red[2][u][m][lane] + red[3][u][m][lane]);
#pragma unroll
                    for (int i = 0; i < 4; ++i)
                        P[(((size_t)kh * 9 + t2) * 64 + (m * 16 + rrow + i)) * 1024 + jc * 16 + rcol]
                            = v[i];
                }
            }
            __syncthreads();
        }
    }
}

// ---------------- step reduce: sum 8 kh-partials + fused GRU pointwise ----------
// T0==3 instantiation (final step) also writes the hidden-state output block.
template <int T0, int T1>
__global__ __launch_bounds__(256)
void step_reduce_kernel(const float* __restrict__ P, const float* __restrict__ gx0next,
                        const float* __restrict__ bw0, const float* __restrict__ bu0,
                        const float* __restrict__ bw1, const float* __restrict__ bu1,
                        const unsigned short* __restrict__ h0hi, const unsigned short* __restrict__ h0lo,
                        const unsigned short* __restrict__ h1hi, const unsigned short* __restrict__ h1lo,
                        unsigned short* __restrict__ h0o_hi, unsigned short* __restrict__ h0o_lo,
                        unsigned short* __restrict__ h1o_hi, unsigned short* __restrict__ h1o_lo,
                        float* __restrict__ outF)
{
    const int idx = blockIdx.x * 256 + threadIdx.x;
    const int b = idx >> 10, j = idx & 1023;
    float G[9];
#pragma unroll
    for (int t2 = T0; t2 < T1; t2++) {
        const float* p = P + ((size_t)t2 * 64 + b) * 1024 + j;
        float s0 = 0.f, s1 = 0.f;
#pragma unroll
        for (int kh = 0; kh < 4; kh++) {
            s0 += p[(size_t)(kh * 9) * 64 * 1024];
            s1 += p[(size_t)((kh + 4) * 9) * 64 * 1024];
        }
        G[t2] = s0 + s1;
    }
    const size_t po = htile_off(b, j);
    if (T0 == 0) {
        float sr  = gx0next[(size_t)b * G3 + j]            + bw0[j]           + G[0] + bu0[j];
        float sz  = gx0next[(size_t)b * G3 + HID + j]      + bw0[HID + j]     + G[1] + bu0[HID + j];
        float gxn = gx0next[(size_t)b * G3 + 2 * HID + j]  + bw0[2 * HID + j];
        float ghn = G[2] + bu0[2 * HID + j];
        float r = sigmoidf_(sr);
        float z = sigmoidf_(sz);
        float ht = tanhf(gxn + r * ghn);
        float hp = bf2f(h0hi[po]) + bf2f(h0lo[po]);
        float hn = (1.f - z) * hp + z * ht;
        unsigned short hh, hl2; split2(hn, hh, hl2);
        h0o_hi[po] = hh; h0o_lo[po] = hl2;
    }
    if (T1 > 3) {
        float sr  = G[3] + bw1[j]           + G[6] + bu1[j];
        float sz  = G[4] + bw1[HID + j]     + G[7] + bu1[HID + j];
        float gxn = G[5] + bw1[2 * HID + j];
        float ghn = G[8] + bu1[2 * HID + j];
        float r = sigmoidf_(sr);
        float z = sigmoidf_(sz);
        float ht = tanhf(gxn + r * ghn);
        float hp = bf2f(h1hi[po]) + bf2f(h1lo[po]);
        float hn = (1.f - z) * hp + z * ht;
        unsigned short hh, hl2; split2(hn, hh, hl2);
        h1o_hi[po] = hh; h1o_lo[po] = hl2;
        if (T0 == 3) {   // final step: emit hidden output (h0_63 from inputs, h1_63 = hn)
            outF[(size_t)b * HID + j] = bf2f(h0hi[po]) + bf2f(h0lo[po]);
            outF[(size_t)BATCHN * HID + b * HID + j] = hn;
        }
    }
}

extern "C" void kernel_launch(void* const* d_in, const int* in_sizes, int n_in,
                              void* d_out, int out_size, void* d_ws, size_t ws_size,
                              hipStream_t stream)
{
    (void)in_sizes; (void)n_in; (void)out_size;
    const int*   tok    = (const int*)  d_in[0];
    const float* hidden = (const float*)d_in[1];
    const float* emb    = (const float*)d_in[2];
    const float* W0     = (const float*)d_in[3];
    const float* U0     = (const float*)d_in[4];
    const float* bw0    = (const float*)d_in[5];
    const float* bu0    = (const float*)d_in[6];
    const float* W1     = (const float*)d_in[7];
    const float* U1     = (const float*)d_in[8];
    const float* bw1    = (const float*)d_in[9];
    const float* bu1    = (const float*)d_in[10];
    const float* fcW    = (const float*)d_in[11];
    const float* fcb    = (const float*)d_in[12];
    float* out = (float*)d_out;

    char* wsp = (char*)d_ws;
    size_t used = 0;
    auto alloc = [&](size_t bytes) -> char* {
        char* p = wsp + used;
        used += (bytes + 255) & ~(size_t)255;
        return p;
    };
    unsigned short* Wt_hi = (unsigned short*)alloc((size_t)4 * G3 * HID * 2);   // 25.2 MB
    unsigned short* Wt_lo = (unsigned short*)alloc((size_t)4 * G3 * HID * 2);   // 25.2 MB
    float*          GX0   = (float*)alloc((size_t)AROWS * G3 * 4);              // 50.3 MB
    unsigned short* H0Thi = (unsigned short*)alloc((size_t)SEQL * HSLOT * 2);   // 8.4 MB
    unsigned short* H0Tlo = (unsigned short*)alloc((size_t)SEQL * HSLOT * 2);
    unsigned short* H1Thi = (unsigned short*)alloc((size_t)SEQL * HSLOT * 2);
    unsigned short* H1Tlo = (unsigned short*)alloc((size_t)SEQL * HSLOT * 2);
    float*          P     = (float*)alloc((size_t)8 * 9 * BATCHN * HID * 4);    // 18.9 MB
    unsigned short* h0ith = (unsigned short*)alloc((size_t)HSLOT * 2);
    unsigned short* h0itl = (unsigned short*)alloc((size_t)HSLOT * 2);
    unsigned short* h1ith = (unsigned short*)alloc((size_t)HSLOT * 2);
    unsigned short* h1itl = (unsigned short*)alloc((size_t)HSLOT * 2);
    if (used > ws_size) return;  // ~154 MB needed

    unsigned short* fcWhi = Wt_hi;   // fc split aliases dead Wt space (20.97 MB < 25.17 MB)
    unsigned short* fcWlo = Wt_lo;
    float*          fcbp  = (float*)((char*)Wt_hi + (size_t)NPAD * HID * 2);

    float* outHid = out + (size_t)AROWS * VOCAB;

    tile_weights_kernel<<<dim3(48, 32, 4), 256, 0, stream>>>(U0, W1, U1, W0, Wt_hi, Wt_lo);
    small_prep_kernel<<<256, 256, 0, stream>>>(hidden, h0ith, h0itl, h1ith, h1itl);
    gx0_gemm_kernel<<<768, 256, 0, stream>>>(tok, emb, Wt_hi, Wt_lo, GX0);

    // prologue: h0_0 = GRU0(gx0[0], h_init0)
    step_gemm_kernel<0, 3><<<512, 256, 0, stream>>>(
        h0ith, h0itl, h1ith, h1itl, Wt_hi, Wt_lo, P);
    step_reduce_kernel<0, 3><<<256, 256, 0, stream>>>(
        P, GX0, bw0, bu0, bw1, bu1,
        h0ith, h0itl, h1ith, h1itl,
        H0Thi, H0Tlo,                                       // h0_0 -> slot 0
        H1Thi + (size_t)63 * HSLOT, H1Tlo + (size_t)63 * HSLOT,   // unused (compiled out)
        outHid);

    for (int t = 0; t < 63; t++) {
        const unsigned short* h0h = H0Thi + (size_t)t * HSLOT;
        const unsigned short* h0l = H0Tlo + (size_t)t * HSLOT;
        const unsigned short* a1h = (t == 0) ? h1ith : H1Thi + (size_t)(t - 1) * HSLOT;
        const unsigned short* a1l = (t == 0) ? h1itl : H1Tlo + (size_t)(t - 1) * HSLOT;
        step_gemm_kernel<0, 9><<<512, 256, 0, stream>>>(
            h0h, h0l, a1h, a1l, Wt_hi, Wt_lo, P);
        step_reduce_kernel<0, 9><<<256, 256, 0, stream>>>(
            P, GX0 + (size_t)(t + 1) * BATCHN * G3, bw0, bu0, bw1, bu1,
            h0h, h0l, a1h, a1l,
            H0Thi + (size_t)(t + 1) * HSLOT, H0Tlo + (size_t)(t + 1) * HSLOT,  // h0_{t+1}
            H1Thi + (size_t)t * HSLOT, H1Tlo + (size_t)t * HSLOT,              // h1_t
            outHid);
    }
    // t = 63: layer-1 only; also emits hidden output (h0_63 + h1_63)
    step_gemm_kernel<3, 9><<<512, 256, 0, stream>>>(
        H0Thi + (size_t)63 * HSLOT, H0Tlo + (size_t)63 * HSLOT,
        H1Thi + (size_t)62 * HSLOT, H1Tlo + (size_t)62 * HSLOT,
        Wt_hi, Wt_lo, P);
    step_reduce_kernel<3, 9><<<256, 256, 0, stream>>>(
        P, GX0, bw0, bu0, bw1, bu1,
        H0Thi + (size_t)63 * HSLOT, H0Tlo + (size_t)63 * HSLOT,
        H1Thi + (size_t)62 * HSLOT, H1Tlo + (size_t)62 * HSLOT,
        h0ith, h0itl,                                              // unused (compiled out)
        H1Thi + (size_t)63 * HSLOT, H1Tlo + (size_t)63 * HSLOT,    // h1_63
        outHid);

    // fc prep (aliases dead Wt space), then logits
    fc_pad_split_kernel<<<NPAD, 256, 0, stream>>>(fcW, fcWhi, fcWlo, fcb, fcbp);
    logits_gemm_kernel<<<2560, 256, 0, stream>>>(
        H1Thi, H1Tlo, fcWhi, fcWlo, fcbp, out);
}

// Round 13
// 1496.259 us; speedup vs baseline: 1.0723x; 1.0446x over previous
//
#include <hip/hip_runtime.h>
#include <math.h>

#define SEQL 64
#define BATCHN 64
#define HID 1024
#define EMBD 1024
#define VOCAB 10000
#define G3 3072
#define NPAD 10240   // 80*128
#define AROWS 4096   // SEQL*BATCHN
#define HSLOT 65536  // BATCHN*HID elements per t-slot

typedef float f4v __attribute__((ext_vector_type(4)));
typedef unsigned short us4 __attribute__((ext_vector_type(4)));
typedef unsigned short us8 __attribute__((ext_vector_type(8)));
typedef __bf16 bf8v __attribute__((ext_vector_type(8)));

__device__ __forceinline__ unsigned short f2bf(float f) {
    unsigned u = __float_as_uint(f);
    u += 0x7fffu + ((u >> 16) & 1u);
    return (unsigned short)(u >> 16);
}
__device__ __forceinline__ float bf2f(unsigned short h) {
    return __uint_as_float(((unsigned)h) << 16);
}
__device__ __forceinline__ void split2(float f, unsigned short &hi, unsigned short &lo) {
    hi = f2bf(f);
    lo = f2bf(f - bf2f(hi));
}
__device__ __forceinline__ f4v mfma16(us8 a, us8 b, f4v c) {
    return __builtin_amdgcn_mfma_f32_16x16x32_bf16(
        __builtin_bit_cast(bf8v, a), __builtin_bit_cast(bf8v, b), c, 0, 0, 0);
}
__device__ __forceinline__ float sigmoidf_(float x) { return 1.f / (1.f + expf(-x)); }

// tiled layout for h within one t-slot: [(b>>4)*32 + (j>>5)][lane=((j>>3)&3)*16+(b&15)][e=j&7]
__device__ __forceinline__ size_t htile_off(int b, int j) {
    return ((size_t)((((b >> 4) * 32 + (j >> 5)) * 64) + ((j >> 3) & 3) * 16 + (b & 15))) * 8 + (j & 7);
}

// ---------------- prep: tile 4 weight matrices into MFMA B-fragment order ----------
// mats: 0=U0, 1=W1, 2=U1, 3=W0
__global__ __launch_bounds__(256)
void tile_weights_kernel(const float* __restrict__ U0, const float* __restrict__ W1,
                         const float* __restrict__ U1, const float* __restrict__ W0,
                         unsigned short* __restrict__ hi, unsigned short* __restrict__ lo)
{
    __shared__ float tile[32][65];
    const int mat = blockIdx.z;
    const float* src = (mat == 0) ? U0 : (mat == 1) ? W1 : (mat == 2) ? U1 : W0;
    const int n0 = blockIdx.x * 64, k0 = blockIdx.y * 32;
    const int t = threadIdx.x, tx = t & 63, ty = t >> 6;
#pragma unroll
    for (int s = 0; s < 8; s++)
        tile[ty * 8 + s][tx] = src[(size_t)(k0 + ty * 8 + s) * G3 + n0 + tx];
    __syncthreads();
    const int c = t >> 6, lane = t & 63, fr = lane & 15, kg = lane >> 4;
    const int cc = (n0 >> 4) + c;
    const size_t off = (((size_t)(mat * 192 + cc) * 32 + (k0 >> 5)) * 64 + lane) * 8;
    us8 h8, l8;
#pragma unroll
    for (int e = 0; e < 8; e++) {
        unsigned short a, b;
        split2(tile[kg * 8 + e][c * 16 + fr], a, b);
        h8[e] = a; l8[e] = b;
    }
    *(us8*)(hi + off) = h8;
    *(us8*)(lo + off) = l8;
}

// ---------------- prep (late): pad fcW to NPAD rows + hi/lo split ; fcb pad merged ----------
__global__ void fc_pad_split_kernel(const float* __restrict__ fcW,
                                    unsigned short* __restrict__ hi, unsigned short* __restrict__ lo,
                                    const float* __restrict__ fcb, float* __restrict__ fcb_pad)
{
    size_t g = (size_t)blockIdx.x * 256 + threadIdx.x;
    if (g < NPAD) fcb_pad[g] = (g < VOCAB) ? fcb[g] : 0.f;
    size_t i = g * 4;
    size_t row = i >> 10;
    f4v v = {0.f, 0.f, 0.f, 0.f};
    if (row < VOCAB) v = *(const f4v*)(fcW + i);
    us4 h, l;
#pragma unroll
    for (int j = 0; j < 4; j++) { unsigned short a, b; split2(v[j], a, b); h[j] = a; l[j] = b; }
    *(us4*)(hi + i) = h;
    *(us4*)(lo + i) = l;
}

// ---------------- prep: initial hidden -> tiled hi/lo ----------
__global__ void small_prep_kernel(const float* __restrict__ hidden,
                                  unsigned short* __restrict__ h0th, unsigned short* __restrict__ h0tl,
                                  unsigned short* __restrict__ h1th, unsigned short* __restrict__ h1tl)
{
    int idx = blockIdx.x * 256 + threadIdx.x;
    if (idx < BATCHN * HID) {
        int b = idx >> 10, j = idx & 1023;
        size_t o = htile_off(b, j);
        unsigned short a1, b1;
        split2(hidden[idx], a1, b1);                 h0th[o] = a1; h0tl[o] = b1;
        split2(hidden[BATCHN * HID + idx], a1, b1);  h1th[o] = a1; h1tl[o] = b1;
    }
}

// ---------------- GX0 = gather(emb,tok) @ W0 ----------
__global__ __launch_bounds__(256)
void gx0_gemm_kernel(const int* __restrict__ tok, const float* __restrict__ emb,
                     const unsigned short* __restrict__ Wthi, const unsigned short* __restrict__ Wtlo,
                     float* __restrict__ C)
{
    __shared__ unsigned short Ah[128][40], Al[128][40];
    const int bswz = blockIdx.x;
    const int xcd = bswz & 7, s = bswz >> 3;
    const int col0 = (xcd + 8 * (s >> 5)) * 128;   // 24 col-tiles
    const int row0 = (s & 31) * 128;               // 32 row-tiles
    const int tid = threadIdx.x;
    const int lane = tid & 63, wave = tid >> 6;
    const int wm = wave >> 1, wn = wave & 1;
    const int srow = tid >> 1;
    const int shalf = (tid & 1) * 16;

    const float* asrc = emb + (size_t)tok[row0 + srow] * EMBD + shalf;
    const int fr = lane & 15, fk = (lane >> 4) * 8;
    const int cc0 = (col0 >> 4) + wn * 4;

    f4v a[4];
#pragma unroll
    for (int q = 0; q < 4; q++) a[q] = *(const f4v*)(asrc + q * 4);

    f4v acc[4][4] = {};
    for (int k0 = 0; k0 < EMBD; k0 += 32) {
        __syncthreads();
        us8 ahv[2], alv[2];
#pragma unroll
        for (int q = 0; q < 4; q++)
#pragma unroll
            for (int j = 0; j < 4; j++) {
                unsigned short h, l;
                split2(a[q][j], h, l);
                ahv[q >> 1][(q & 1) * 4 + j] = h;
                alv[q >> 1][(q & 1) * 4 + j] = l;
            }
        *(us8*)(&Ah[srow][shalf]) = ahv[0];     *(us8*)(&Ah[srow][shalf + 8]) = ahv[1];
        *(us8*)(&Al[srow][shalf]) = alv[0];     *(us8*)(&Al[srow][shalf + 8]) = alv[1];
        __syncthreads();
        if (k0 + 32 < EMBD) {
#pragma unroll
            for (int q = 0; q < 4; q++) a[q] = *(const f4v*)(asrc + k0 + 32 + q * 4);
        }
        const int ks = k0 >> 5;
        us8 bfh[4], bfl[4];
#pragma unroll
        for (int n = 0; n < 4; n++) {
            const size_t bo = (((size_t)(3 * 192 + cc0 + n) * 32 + ks) * 64 + lane) * 8;
            bfh[n] = *(const us8*)(Wthi + bo);
            bfl[n] = *(const us8*)(Wtlo + bo);
        }
        us8 afh[4], afl[4];
#pragma unroll
        for (int m = 0; m < 4; m++) {
            afh[m] = *(const us8*)(&Ah[wm * 64 + m * 16 + fr][fk]);
            afl[m] = *(const us8*)(&Al[wm * 64 + m * 16 + fr][fk]);
        }
#pragma unroll
        for (int n = 0; n < 4; n++)
#pragma unroll
            for (int m = 0; m < 4; m++) {
                acc[m][n] = mfma16(afh[m], bfh[n], acc[m][n]);
                acc[m][n] = mfma16(afh[m], bfl[n], acc[m][n]);
                acc[m][n] = mfma16(afl[m], bfh[n], acc[m][n]);
            }
    }
    const int fq = lane >> 4;
#pragma unroll
    for (int m = 0; m < 4; m++)
#pragma unroll
        for (int n = 0; n < 4; n++)
#pragma unroll
            for (int i = 0; i < 4; i++) {
                int r = row0 + wm * 64 + m * 16 + fq * 4 + i;
                int c = col0 + wn * 64 + n * 16 + fr;
                C[(size_t)r * G3 + c] = acc[m][n][i];
            }
}

// ---------------- logits = H1 @ fcW^T + fcb ; exact R7 form (best measured: 266 us) ----------
__global__ __launch_bounds__(256)
void logits_gemm_kernel(const unsigned short* __restrict__ h1t_hi, const unsigned short* __restrict__ h1t_lo,
                        const unsigned short* __restrict__ Bhi, const unsigned short* __restrict__ Blo,
                        const float* __restrict__ bias, float* __restrict__ C)
{
    __shared__ unsigned short Bh[128][40], Bl[128][40];
    const int bswz = blockIdx.x;
    const int xcd = bswz & 7, s = bswz >> 3;
    const int col0 = (xcd + 8 * (s >> 5)) * 128;   // 80 col-tiles
    const int row0 = (s & 31) * 128;               // 32 row-tiles
    const int t0 = row0 >> 6;                       // 2 t-slots per 128-row tile
    const int tid = threadIdx.x;
    const int lane = tid & 63, wave = tid >> 6;
    const int wm = wave >> 1, wn = wave & 1;
    const int srow = tid >> 1;
    const int shalf = (tid & 1) * 16;

    const unsigned short* bh_src = Bhi + (size_t)(col0 + srow) * HID + shalf;
    const unsigned short* bl_src = Blo + (size_t)(col0 + srow) * HID + shalf;

    f4v acc[4][4] = {};
    us8 bh2[2], bl2[2];
    bh2[0] = *(const us8*)(bh_src);  bh2[1] = *(const us8*)(bh_src + 8);
    bl2[0] = *(const us8*)(bl_src);  bl2[1] = *(const us8*)(bl_src + 8);

    const int fr = lane & 15, fk = (lane >> 4) * 8;
    const size_t abase = ((size_t)(t0 + wm) * 128) * 512 + (size_t)lane * 8;

    for (int k0 = 0; k0 < HID; k0 += 32) {
        __syncthreads();
        *(us8*)(&Bh[srow][shalf]) = bh2[0];  *(us8*)(&Bh[srow][shalf + 8]) = bh2[1];
        *(us8*)(&Bl[srow][shalf]) = bl2[0];  *(us8*)(&Bl[srow][shalf + 8]) = bl2[1];
        __syncthreads();
        if (k0 + 32 < HID) {
            bh2[0] = *(const us8*)(bh_src + k0 + 32);  bh2[1] = *(const us8*)(bh_src + k0 + 40);
            bl2[0] = *(const us8*)(bl_src + k0 + 32);  bl2[1] = *(const us8*)(bl_src + k0 + 40);
        }
        const int ks = k0 >> 5;
        us8 afh[4], afl[4];
#pragma unroll
        for (int m = 0; m < 4; m++) {
            const size_t ao = abase + (size_t)(m * 32 + ks) * 512;
            afh[m] = *(const us8*)(h1t_hi + ao);
            afl[m] = *(const us8*)(h1t_lo + ao);
        }
#pragma unroll
        for (int n = 0; n < 4; n++) {
            us8 bfh = *(const us8*)(&Bh[wn * 64 + n * 16 + fr][fk]);
            us8 bfl = *(const us8*)(&Bl[wn * 64 + n * 16 + fr][fk]);
#pragma unroll
            for (int m = 0; m < 4; m++) {
                acc[m][n] = mfma16(afh[m], bfh, acc[m][n]);
                acc[m][n] = mfma16(afh[m], bfl, acc[m][n]);
                acc[m][n] = mfma16(afl[m], bfh, acc[m][n]);
            }
        }
    }
    const int fq = lane >> 4;
#pragma unroll
    for (int m = 0; m < 4; m++)
#pragma unroll
        for (int n = 0; n < 4; n++)
#pragma unroll
            for (int i = 0; i < 4; i++) {
                int r = row0 + wm * 64 + m * 16 + fq * 4 + i;
                int c = col0 + wn * 64 + n * 16 + fr;
                float v = acc[m][n][i] + bias[c];
                if (c < VOCAB) C[(size_t)r * VOCAB + c] = v;
            }
}

// ---------------- step GEMM: grid 512 = 64 jc x 8 kh, 256 thr (R10, proven) ----------
template <int T0, int T1>
__global__ __launch_bounds__(256)
void step_gemm_kernel(const unsigned short* __restrict__ h0hi, const unsigned short* __restrict__ h0lo,
                      const unsigned short* __restrict__ h1hi, const unsigned short* __restrict__ h1lo,
                      const unsigned short* __restrict__ Wthi, const unsigned short* __restrict__ Wtlo,
                      float* __restrict__ P)
{
    const int tid = threadIdx.x, lane = tid & 63, wave = tid >> 6;
    const int jc = blockIdx.x >> 3, kh = blockIdx.x & 7;
    const int ks = kh * 4 + wave;
    const size_t abase = ((size_t)ks * 64 + lane) * 8;

    f4v acc[9][4] = {};
    us8 ah[4], al[4];

    if (T0 < 6) {
#pragma unroll
        for (int m = 0; m < 4; m++) {
            ah[m] = *(const us8*)(h0hi + abase + (size_t)m * 16384);
            al[m] = *(const us8*)(h0lo + abase + (size_t)m * 16384);
        }
#pragma unroll
        for (int t2 = T0; t2 < ((T1 < 6) ? T1 : 6); ++t2) {
            const int mat = t2 / 3, g = t2 % 3;
            const size_t base = (((size_t)(mat * 192 + g * 64 + jc) * 32 + ks) * 64 + lane) * 8;
            us8 bh = *(const us8*)(Wthi + base);
            us8 bl = *(const us8*)(Wtlo + base);
#pragma unroll
            for (int m = 0; m < 4; ++m) {
                acc[t2][m] = mfma16(ah[m], bh, acc[t2][m]);
                acc[t2][m] = mfma16(ah[m], bl, acc[t2][m]);
                acc[t2][m] = mfma16(al[m], bh, acc[t2][m]);
            }
        }
    }
    if (T1 > 6) {
#pragma unroll
        for (int m = 0; m < 4; m++) {
            ah[m] = *(const us8*)(h1hi + abase + (size_t)m * 16384);
            al[m] = *(const us8*)(h1lo + abase + (size_t)m * 16384);
        }
#pragma unroll
        for (int t2 = 6; t2 < T1; ++t2) {
            const int g = t2 % 3;
            const size_t base = (((size_t)(2 * 192 + g * 64 + jc) * 32 + ks) * 64 + lane) * 8;
            us8 bh = *(const us8*)(Wthi + base);
            us8 bl = *(const us8*)(Wtlo + base);
#pragma unroll
            for (int m = 0; m < 4; ++m) {
                acc[t2][m] = mfma16(ah[m], bh, acc[t2][m]);
                acc[t2][m] = mfma16(ah[m], bl, acc[t2][m]);
                acc[t2][m] = mfma16(al[m], bh, acc[t2][m]);
            }
        }
    }

    __shared__ f4v red[4][2][4][64];
    const int rrow = (lane >> 4) * 4, rcol = lane & 15;
#pragma unroll
    for (int c = 0; c < 5; ++c) {
        const int ta = 2 * c, tb = 2 * c + 1;
        if (tb >= T0 && ta < T1) {
#pragma unroll
            for (int u = 0; u < 2; ++u) {
                const int t2 = 2 * c + u;
                if (t2 >= T0 && t2 < T1) {
#pragma unroll
                    for (int m = 0; m < 4; ++m)
                        red[wave][u][m][lane] = acc[t2][m];
                }
            }
            __syncthreads();
#pragma unroll
            for (int s2 = 0; s2 < 2; ++s2) {
                const int combo = wave * 2 + s2;       // 0..7
                const int u = combo >> 2, m = combo & 3;
                const int t2 = 2 * c + u;
                if (t2 >= T0 && t2 < T1) {
                    f4v v = (red[0][u][m][lane] + red[1][u][m][lane])
                          + (red[2][u][m][lane] + red[3][u][m][lane]);
#pragma unroll
                    for (int i = 0; i < 4; ++i)
                        P[(((size_t)kh * 9 + t2) * 64 + (m * 16 + rrow + i)) * 1024 + jc * 16 + rcol]
                            = v[i];
                }
            }
            __syncthreads();
        }
    }
}

// ---------------- step reduce: sum 8 kh-partials + fused GRU pointwise ----------
// T0==3 instantiation (final step) also writes the hidden-state output block.
template <int T0, int T1>
__global__ __launch_bounds__(256)
void step_reduce_kernel(const float* __restrict__ P, const float* __restrict__ gx0next,
                        const float* __restrict__ bw0, const float* __restrict__ bu0,
                        const float* __restrict__ bw1, const float* __restrict__ bu1,
                        const unsigned short* __restrict__ h0hi, const unsigned short* __restrict__ h0lo,
                        const unsigned short* __restrict__ h1hi, const unsigned short* __restrict__ h1lo,
                        unsigned short* __restrict__ h0o_hi, unsigned short* __restrict__ h0o_lo,
                        unsigned short* __restrict__ h1o_hi, unsigned short* __restrict__ h1o_lo,
                        float* __restrict__ outF)
{
    const int idx = blockIdx.x * 256 + threadIdx.x;
    const int b = idx >> 10, j = idx & 1023;
    float G[9];
#pragma unroll
    for (int t2 = T0; t2 < T1; t2++) {
        const float* p = P + ((size_t)t2 * 64 + b) * 1024 + j;
        float s0 = 0.f, s1 = 0.f;
#pragma unroll
        for (int kh = 0; kh < 4; kh++) {
            s0 += p[(size_t)(kh * 9) * 64 * 1024];
            s1 += p[(size_t)((kh + 4) * 9) * 64 * 1024];
        }
        G[t2] = s0 + s1;
    }
    const size_t po = htile_off(b, j);
    if (T0 == 0) {
        float sr  = gx0next[(size_t)b * G3 + j]            + bw0[j]           + G[0] + bu0[j];
        float sz  = gx0next[(size_t)b * G3 + HID + j]      + bw0[HID + j]     + G[1] + bu0[HID + j];
        float gxn = gx0next[(size_t)b * G3 + 2 * HID + j]  + bw0[2 * HID + j];
        float ghn = G[2] + bu0[2 * HID + j];
        float r = sigmoidf_(sr);
        float z = sigmoidf_(sz);
        float ht = tanhf(gxn + r * ghn);
        float hp = bf2f(h0hi[po]) + bf2f(h0lo[po]);
        float hn = (1.f - z) * hp + z * ht;
        unsigned short hh, hl2; split2(hn, hh, hl2);
        h0o_hi[po] = hh; h0o_lo[po] = hl2;
    }
    if (T1 > 3) {
        float sr  = G[3] + bw1[j]           + G[6] + bu1[j];
        float sz  = G[4] + bw1[HID + j]     + G[7] + bu1[HID + j];
        float gxn = G[5] + bw1[2 * HID + j];
        float ghn = G[8] + bu1[2 * HID + j];
        float r = sigmoidf_(sr);
        float z = sigmoidf_(sz);
        float ht = tanhf(gxn + r * ghn);
        float hp = bf2f(h1hi[po]) + bf2f(h1lo[po]);
        float hn = (1.f - z) * hp + z * ht;
        unsigned short hh, hl2; split2(hn, hh, hl2);
        h1o_hi[po] = hh; h1o_lo[po] = hl2;
        if (T0 == 3) {   // final step: emit hidden output (h0_63 from inputs, h1_63 = hn)
            outF[(size_t)b * HID + j] = bf2f(h0hi[po]) + bf2f(h0lo[po]);
            outF[(size_t)BATCHN * HID + b * HID + j] = hn;
        }
    }
}

extern "C" void kernel_launch(void* const* d_in, const int* in_sizes, int n_in,
                              void* d_out, int out_size, void* d_ws, size_t ws_size,
                              hipStream_t stream)
{
    (void)in_sizes; (void)n_in; (void)out_size;
    const int*   tok    = (const int*)  d_in[0];
    const float* hidden = (const float*)d_in[1];
    const float* emb    = (const float*)d_in[2];
    const float* W0     = (const float*)d_in[3];
    const float* U0     = (const float*)d_in[4];
    const float* bw0    = (const float*)d_in[5];
    const float* bu0    = (const float*)d_in[6];
    const float* W1     = (const float*)d_in[7];
    const float* U1     = (const float*)d_in[8];
    const float* bw1    = (const float*)d_in[9];
    const float* bu1    = (const float*)d_in[10];
    const float* fcW    = (const float*)d_in[11];
    const float* fcb    = (const float*)d_in[12];
    float* out = (float*)d_out;

    char* wsp = (char*)d_ws;
    size_t used = 0;
    auto alloc = [&](size_t bytes) -> char* {
        char* p = wsp + used;
        used += (bytes + 255) & ~(size_t)255;
        return p;
    };
    unsigned short* Wt_hi = (unsigned short*)alloc((size_t)4 * G3 * HID * 2);   // 25.2 MB
    unsigned short* Wt_lo = (unsigned short*)alloc((size_t)4 * G3 * HID * 2);   // 25.2 MB
    float*          GX0   = (float*)alloc((size_t)AROWS * G3 * 4);              // 50.3 MB
    unsigned short* H0Thi = (unsigned short*)alloc((size_t)SEQL * HSLOT * 2);   // 8.4 MB
    unsigned short* H0Tlo = (unsigned short*)alloc((size_t)SEQL * HSLOT * 2);
    unsigned short* H1Thi = (unsigned short*)alloc((size_t)SEQL * HSLOT * 2);
    unsigned short* H1Tlo = (unsigned short*)alloc((size_t)SEQL * HSLOT * 2);
    float*          P     = (float*)alloc((size_t)8 * 9 * BATCHN * HID * 4);    // 18.9 MB
    unsigned short* h0ith = (unsigned short*)alloc((size_t)HSLOT * 2);
    unsigned short* h0itl = (unsigned short*)alloc((size_t)HSLOT * 2);
    unsigned short* h1ith = (unsigned short*)alloc((size_t)HSLOT * 2);
    unsigned short* h1itl = (unsigned short*)alloc((size_t)HSLOT * 2);
    if (used > ws_size) return;  // ~154 MB needed

    unsigned short* fcWhi = Wt_hi;   // fc split aliases dead Wt space (20.97 MB < 25.17 MB)
    unsigned short* fcWlo = Wt_lo;
    float*          fcbp  = (float*)((char*)Wt_hi + (size_t)NPAD * HID * 2);

    float* outHid = out + (size_t)AROWS * VOCAB;

    tile_weights_kernel<<<dim3(48, 32, 4), 256, 0, stream>>>(U0, W1, U1, W0, Wt_hi, Wt_lo);
    small_prep_kernel<<<256, 256, 0, stream>>>(hidden, h0ith, h0itl, h1ith, h1itl);
    gx0_gemm_kernel<<<768, 256, 0, stream>>>(tok, emb, Wt_hi, Wt_lo, GX0);

    // prologue: h0_0 = GRU0(gx0[0], h_init0)
    step_gemm_kernel<0, 3><<<512, 256, 0, stream>>>(
        h0ith, h0itl, h1ith, h1itl, Wt_hi, Wt_lo, P);
    step_reduce_kernel<0, 3><<<256, 256, 0, stream>>>(
        P, GX0, bw0, bu0, bw1, bu1,
        h0ith, h0itl, h1ith, h1itl,
        H0Thi, H0Tlo,                                       // h0_0 -> slot 0
        H1Thi + (size_t)63 * HSLOT, H1Tlo + (size_t)63 * HSLOT,   // unused (compiled out)
        outHid);

    for (int t = 0; t < 63; t++) {
        const unsigned short* h0h = H0Thi + (size_t)t * HSLOT;
        const unsigned short* h0l = H0Tlo + (size_t)t * HSLOT;
        const unsigned short* a1h = (t == 0) ? h1ith : H1Thi + (size_t)(t - 1) * HSLOT;
        const unsigned short* a1l = (t == 0) ? h1itl : H1Tlo + (size_t)(t - 1) * HSLOT;
        step_gemm_kernel<0, 9><<<512, 256, 0, stream>>>(
            h0h, h0l, a1h, a1l, Wt_hi, Wt_lo, P);
        step_reduce_kernel<0, 9><<<256, 256, 0, stream>>>(
            P, GX0 + (size_t)(t + 1) * BATCHN * G3, bw0, bu0, bw1, bu1,
            h0h, h0l, a1h, a1l,
            H0Thi + (size_t)(t + 1) * HSLOT, H0Tlo + (size_t)(t + 1) * HSLOT,  // h0_{t+1}
            H1Thi + (size_t)t * HSLOT, H1Tlo + (size_t)t * HSLOT,              // h1_t
            outHid);
    }
    // t = 63: layer-1 only; also emits hidden output (h0_63 + h1_63)
    step_gemm_kernel<3, 9><<<512, 256, 0, stream>>>(
        H0Thi + (size_t)63 * HSLOT, H0Tlo + (size_t)63 * HSLOT,
        H1Thi + (size_t)62 * HSLOT, H1Tlo + (size_t)62 * HSLOT,
        Wt_hi, Wt_lo, P);
    step_reduce_kernel<3, 9><<<256, 256, 0, stream>>>(
        P, GX0, bw0, bu0, bw1, bu1,
        H0Thi + (size_t)63 * HSLOT, H0Tlo + (size_t)63 * HSLOT,
        H1Thi + (size_t)62 * HSLOT, H1Tlo + (size_t)62 * HSLOT,
        h0ith, h0itl,                                              // unused (compiled out)
        H1Thi + (size_t)63 * HSLOT, H1Tlo + (size_t)63 * HSLOT,    // h1_63
        outHid);

    // fc prep (aliases dead Wt space), then logits
    fc_pad_split_kernel<<<NPAD, 256, 0, stream>>>(fcW, fcWhi, fcWlo, fcb, fcbp);
    logits_gemm_kernel<<<2560, 256, 0, stream>>>(
        H1Thi, H1Tlo, fcWhi, fcWlo, fcbp, out);
}